// Round 15
// baseline (567.855 us; speedup 1.0000x reference)
//
#include <hip/hip_runtime.h>
#include <math.h>

// ---------------------------------------------------------------------------
// N=64, L=128, W=256, D=384, H=8, E=48, NL=4, DFF=1536, rows = N*L = 8192
// GEMMs: bf16 MFMA 16x16x32, A [M][K] bf16 row-major, Bt [N][K] bf16.
// R32: cnn -> 2 WAVES per block (128 thr, 2 windows, still ZERO barriers;
// each wave owns a disjoint 6.7KB LDS slice, internals byte-identical to
// R31 per window -> same numerics, absmax 9.8e-4 from R30's conv1-bf16).
// Post-mortem R31: 562.8us best; occupancy stuck ~35% despite 7KB LDS ->
// the binding limit is the HW max-workgroups/CU (~16) with 1-wave blocks.
// 2 waves/block: 16 blk x 2 = 32-wave ceiling, LDS limit ~12 blk -> ~24
// waves/CU (~2x residency), same zero-sync structure.
// ---------------------------------------------------------------------------

typedef float f32x4 __attribute__((ext_vector_type(4)));
typedef short bf16x8 __attribute__((ext_vector_type(8)));
typedef short s16x4 __attribute__((ext_vector_type(4)));

__device__ __forceinline__ short f2bf(float f) {
    union { float f; unsigned u; } c; c.f = f;
    unsigned r = (c.u + 0x7FFFu + ((c.u >> 16) & 1u)) >> 16;
    return (short)r;
}
__device__ __forceinline__ float bf2f(short s) {
    union { unsigned u; float f; } c;
    c.u = ((unsigned)(unsigned short)s) << 16;
    return c.f;
}

__device__ __forceinline__ void gload_lds16(const void* g, void* l) {
    __builtin_amdgcn_global_load_lds(
        (const __attribute__((address_space(1))) unsigned int*)g,
        (__attribute__((address_space(3))) unsigned int*)l,
        16, 0, 0);
}

// ---------------- merged prep: weight cvt + pe + biascat + w2cvt + w1cvt ---
__global__ __launch_bounds__(256) void prep_kernel(
    const float* __restrict__ ew,
    const float* __restrict__ Wq, const float* __restrict__ Wk,
    const float* __restrict__ Wv, const float* __restrict__ Wo,
    const float* __restrict__ W1, const float* __restrict__ W2,
    const float* __restrict__ bq, const float* __restrict__ bk,
    const float* __restrict__ bv, const float* __restrict__ w2,
    const float* __restrict__ w1c,
    short* __restrict__ ewT, short* __restrict__ WqkvT,
    short* __restrict__ WoT, short* __restrict__ W1T,
    short* __restrict__ W2T, float* __restrict__ pe,
    float* __restrict__ bqkv, short* __restrict__ w2T,
    short* __restrict__ w1m)
{
    __shared__ float tile[32][33];
    int id = blockIdx.x;
    int tid = threadIdx.x;
    int tx = tid & 31, ty = tid >> 5;

    const float* Wp;
    short* Wtp;
    int K, N, kb, nb;

    if (id < 768) {
        K = 2048; N = 384;
        kb = (id & 63) * 32; nb = (id >> 6) * 32;
        Wp = ew; Wtp = ewT;
    } else if (id < 2496) {
        int t = id - 768;
        int kbi = t % 12, nbi = (t / 12) % 12, z = t / 144;
        int layer = z / 3, which = z - layer * 3;
        K = 384; N = 384; kb = kbi * 32; nb = nbi * 32;
        Wp = (which == 0 ? Wq : (which == 1 ? Wk : Wv)) + (size_t)layer * 147456;
        Wtp = WqkvT + (size_t)layer * 442368 + (size_t)which * 147456;
    } else if (id < 3072) {
        int t = id - 2496;
        int kbi = t % 12, nbi = (t / 12) % 12, z = t / 144;
        K = 384; N = 384; kb = kbi * 32; nb = nbi * 32;
        Wp = Wo + (size_t)z * 147456; Wtp = WoT + (size_t)z * 147456;
    } else if (id < 5376) {
        int t = id - 3072;
        int kbi = t % 12, nbi = (t / 12) % 48, z = t / 576;
        K = 384; N = 1536; kb = kbi * 32; nb = nbi * 32;
        Wp = W1 + (size_t)z * 589824; Wtp = W1T + (size_t)z * 589824;
    } else if (id < 7680) {
        int t = id - 5376;
        int kbi = t % 48, nbi = (t / 48) % 12, z = t / 576;
        K = 1536; N = 384; kb = kbi * 32; nb = nbi * 32;
        Wp = W2 + (size_t)z * 589824; Wtp = W2T + (size_t)z * 589824;
    } else if (id < 7872) {
        int idx = (id - 7680) * 256 + tid;
        int l = idx / 384, d = idx - l * 384;
        int i2 = d >> 1;
        float ang = (float)l * expf(-(2.0f * (float)i2 / 384.0f) * 9.210340371976184f);
        pe[idx] = (d & 1) ? cosf(ang) : sinf(ang);
        return;
    } else if (id < 7890) {
        int idx = (id - 7872) * 256 + tid;
        int l = idx / 1152, j3 = idx - l * 1152;
        int which = j3 / 384, j = j3 - which * 384;
        const float* b = (which == 0 ? bq : (which == 1 ? bk : bv));
        bqkv[idx] = b[l * 384 + j];
        return;
    } else if (id < 7922) {
        int idx = (id - 7890) * 256 + tid;
        int c = idx >> 7, r = idx & 127;
        int pr = r >> 5, q = (r >> 3) & 3, j = r & 7;
        int ci = (q & 1) * 8 + j;
        int sft = 2 * pr + (q >> 1);
        w2T[idx] = (sft < 7) ? f2bf(w2[c * 112 + ci * 7 + sft]) : (short)0;
        return;
    } else {
        int idx = (id - 7922) * 256 + tid;   // 0..1023
        int t = idx >> 9, ch = (idx >> 5) & 15, k = idx & 31;
        int q = k >> 3, j = k & 7;
        int s = t * 4 + q;
        w1m[idx] = (j < 4 && s < 7) ? f2bf(w1c[(ch * 4 + j) * 7 + s]) : (short)0;
        return;
    }

    #pragma unroll
    for (int r = ty; r < 32; r += 8)
        tile[r][tx] = Wp[(size_t)(kb + r) * N + nb + tx];
    __syncthreads();
    #pragma unroll
    for (int r = ty; r < 32; r += 8)
        Wtp[(size_t)(nb + r) * K + kb + tx] = f2bf(tile[tx][r]);
}

// ---------------- fused CNN window encoder: 2 waves/block, 0 barriers ------
// Per-wave LDS slice (6688 B, wave w at offset w*6688; total 13376 B):
//   [0    .. 1056)  xs[264] f32  (x at idx j+4, zeros [0..3],[260..263])
//   [1056 .. 3216)  p0T8[135][8] bf16 (row = pre-pool pos + 3; slots
//                   0..3 = ci, 4..7 = 0; rows 0..2, 131..134 zero)
//   [3216 .. 6672)  p1T[72][24] bf16 (row = pos+3, pad rows zeroed)
__global__ __launch_bounds__(128) void cnn_kernel(
    const float* __restrict__ x,
    const float* __restrict__ w0, const float* __restrict__ b0,
    const short* __restrict__ w1m, const float* __restrict__ b1,
    const short* __restrict__ w2T, const float* __restrict__ b2,
    short* __restrict__ feat)
{
    __shared__ __align__(16) char smem[13376];
    int tid = threadIdx.x;
    int w = tid >> 6, lane = tid & 63;
    char* sw = smem + w * 6688;
    float* xs   = (float*)sw;                     // [264]
    short* p0T8 = (short*)(sw + 1056);            // [135][8]
    short* p1T  = (short*)(sw + 3216);            // [72][24]

    size_t win = (size_t)blockIdx.x * 2 + w;
    int cq = lane >> 4, cl = lane & 15;

    // ---- setup: w0 to regs, xs fill, zero p0T8 ----
    int ca = lane & 3;
    float w0r[7];
    float b0r = b0[ca];
    #pragma unroll
    for (int k = 0; k < 7; ++k) w0r[k] = w0[ca * 7 + k];

    {
        f32x4 v = *(const f32x4*)(x + win * 256 + lane * 4);
        *(f32x4*)&xs[4 + lane * 4] = v;
        if (lane < 2) *(f32x4*)&xs[lane * 260] = (f32x4){0.f, 0.f, 0.f, 0.f};
    }
    {
        int* pz = (int*)p0T8;                     // 540 dwords
        #pragma unroll
        for (int i = 0; i < 9; ++i) {
            int idx = i * 64 + lane;
            if (idx < 540) pz[idx] = 0;
        }
    }

    // ---- stage A: conv0 + relu + pool2 -> p0T8 rows 3..130 ----
    {
        int pa = lane >> 2;
        #pragma unroll
        for (int t2 = 0; t2 < 8; ++t2) {
            int pp = t2 * 16 + pa;
            float rv[9];
            #pragma unroll
            for (int u = 0; u < 9; ++u) rv[u] = xs[2 * pp + u + 1];
            float a0 = b0r, a1 = b0r;
            #pragma unroll
            for (int k = 0; k < 7; ++k) {
                a0 = fmaf(w0r[k], rv[k], a0);
                a1 = fmaf(w0r[k], rv[k + 1], a1);
            }
            p0T8[(pp + 3) * 8 + ca] = f2bf(fmaxf(fmaxf(a0, a1), 0.f));
        }
    }

    // ---- stage B: conv1 via MFMA paired-shift + pool -> p1T ----
    {
        bf16x8 w1f0 = *(const bf16x8*)&w1m[cl * 32 + cq * 8];
        bf16x8 w1f1 = *(const bf16x8*)&w1m[512 + cl * 32 + cq * 8];
        f32x4 b1v = *(const f32x4*)&b1[cq * 4];
        #pragma unroll
        for (int pt = 0; pt < 8; ++pt) {
            f32x4 hacc = (f32x4){0.f, 0.f, 0.f, 0.f};
            bf16x8 bf0 = *(const bf16x8*)&p0T8[(pt * 16 + cl + cq) * 8];
            hacc = __builtin_amdgcn_mfma_f32_16x16x32_bf16(w1f0, bf0, hacc, 0, 0, 0);
            bf16x8 bf1 = *(const bf16x8*)&p0T8[(pt * 16 + cl + 4 + cq) * 8];
            hacc = __builtin_amdgcn_mfma_f32_16x16x32_bf16(w1f1, bf1, hacc, 0, 0, 0);
            #pragma unroll
            for (int rg = 0; rg < 4; ++rg) {
                float v = hacc[rg] + b1v[rg];
                float v2 = __shfl_xor(v, 1, 64);
                if ((cl & 1) == 0) {
                    int po = (pt * 16 + cl) >> 1;
                    p1T[(3 + po) * 24 + cq * 4 + rg] =
                        f2bf(fmaxf(fmaxf(v, v2), 0.f));
                }
            }
        }
    }
    // zero p1T pad rows: rows 0..2 (dwords 0..35), 67..71 (804..863)
    {
        int* pz = (int*)p1T;
        if (lane < 36) pz[lane] = 0;
        if (lane < 60) pz[804 + lane] = 0;
    }
    // NO barrier: everything below is wave-local (LDS ops ordered in-wave)

    // ---- stage C: conv2 as 4 paired-shift GEMMs, 2 pos-tiles x 4 ch-tiles -
    f32x4 acc[2][4];   // [pos tile pt][channel tile mt]
    #pragma unroll
    for (int pt = 0; pt < 2; ++pt)
        #pragma unroll
        for (int mt = 0; mt < 4; ++mt)
            acc[pt][mt] = (f32x4){0.f, 0.f, 0.f, 0.f};

    {
        const short* bpb0 = p1T + (cl + (cq >> 1)) * 24 + (cq & 1) * 8;
        const short* bpb1 = bpb0 + 16 * 24;
        #pragma unroll
        for (int pr = 0; pr < 4; ++pr) {
            bf16x8 bfr0 = *(const bf16x8*)&bpb0[pr * 48];
            bf16x8 bfr1 = *(const bf16x8*)&bpb1[pr * 48];
            #pragma unroll
            for (int mt = 0; mt < 4; ++mt) {
                bf16x8 af = *(const bf16x8*)&w2T[(mt * 16 + cl) * 128 +
                                                 pr * 32 + cq * 8];
                acc[0][mt] = __builtin_amdgcn_mfma_f32_16x16x32_bf16(
                    af, bfr0, acc[0][mt], 0, 0, 0);
                acc[1][mt] = __builtin_amdgcn_mfma_f32_16x16x32_bf16(
                    af, bfr1, acc[1][mt], 0, 0, 0);
            }
        }
    }

    // ---- epilogue: pool pairs via shfl, store bf16 ----
    short* fp = feat + win * 2048;
    #pragma unroll
    for (int pt = 0; pt < 2; ++pt) {
        int iev = (pt * 16 + cl) >> 1;
        #pragma unroll
        for (int mt = 0; mt < 4; ++mt) {
            #pragma unroll
            for (int rg = 0; rg < 4; ++rg) {
                float vv = acc[pt][mt][rg];
                float v2 = __shfl_xor(vv, 1, 64);
                if ((cl & 1) == 0) {
                    int c = mt * 16 + cq * 4 + rg;
                    float pv = fmaxf(fmaxf(vv, v2) + b2[c], 0.f);
                    fp[c * 32 + iev] = f2bf(pv);
                }
            }
        }
    }
}

// ---------------- bf16 MFMA GEMM (thin-N): BM=128, BN=64, double-buffered --
template <int EPI>
__global__ __launch_bounds__(256) void gemm_bf16(
    const short* __restrict__ A, const short* __restrict__ Bt,
    const float* __restrict__ bias, const float* __restrict__ resid,
    const float* __restrict__ pe, float* __restrict__ outF,
    short* __restrict__ outB, int M, int N, int K)
{
    __shared__ short As[2][128 * 64];
    __shared__ short Bs[2][64 * 64];
    int tid = threadIdx.x;
    int w = tid >> 6, lane = tid & 63;
    int wm = w >> 1, wn = w & 1;
    int m0 = blockIdx.y * 128, n0 = blockIdx.x * 64;

    int rl = lane >> 3, sl = lane & 7;
    int cb = sl ^ rl;
    const short* aptr[4];
    const short* bptr[2];
    int arow[4], brow[2];
    #pragma unroll
    for (int l = 0; l < 4; ++l) {
        arow[l] = l * 32 + w * 8;
        aptr[l] = A + (size_t)(m0 + arow[l] + rl) * K + cb * 8;
    }
    #pragma unroll
    for (int l = 0; l < 2; ++l) {
        brow[l] = l * 32 + w * 8;
        bptr[l] = Bt + (size_t)(n0 + brow[l] + rl) * K + cb * 8;
    }

    int cq = lane >> 4, cl = lane & 15;
    f32x4 acc[4][2];
    #pragma unroll
    for (int mt = 0; mt < 4; ++mt)
        #pragma unroll
        for (int nt = 0; nt < 2; ++nt)
            acc[mt][nt] = (f32x4){0.f, 0.f, 0.f, 0.f};

    #pragma unroll
    for (int l = 0; l < 4; ++l) { gload_lds16(aptr[l], &As[0][arow[l] * 64]); aptr[l] += 64; }
    #pragma unroll
    for (int l = 0; l < 2; ++l) { gload_lds16(bptr[l], &Bs[0][brow[l] * 64]); bptr[l] += 64; }
    __syncthreads();

    int nk = K >> 6;
    for (int k = 0; k < nk; ++k) {
        int cur = k & 1;
        if (k + 1 < nk) {
            #pragma unroll
            for (int l = 0; l < 4; ++l) { gload_lds16(aptr[l], &As[cur ^ 1][arow[l] * 64]); aptr[l] += 64; }
            #pragma unroll
            for (int l = 0; l < 2; ++l) { gload_lds16(bptr[l], &Bs[cur ^ 1][brow[l] * 64]); bptr[l] += 64; }
        }
        #pragma unroll
        for (int s = 0; s < 2; ++s) {
            bf16x8 afr[4], bfr[2];
            #pragma unroll
            for (int mt = 0; mt < 4; ++mt) {
                int r = wm * 64 + mt * 16 + cl;
                int slot = (s * 4 + cq) ^ (r & 7);
                afr[mt] = *(const bf16x8*)&As[cur][r * 64 + slot * 8];
            }
            #pragma unroll
            for (int nt = 0; nt < 2; ++nt) {
                int r = wn * 32 + nt * 16 + cl;
                int slot = (s * 4 + cq) ^ (r & 7);
                bfr[nt] = *(const bf16x8*)&Bs[cur][r * 64 + slot * 8];
            }
            #pragma unroll
            for (int mt = 0; mt < 4; ++mt)
                #pragma unroll
                for (int nt = 0; nt < 2; ++nt)
                    acc[mt][nt] = __builtin_amdgcn_mfma_f32_16x16x32_bf16(
                        afr[mt], bfr[nt], acc[mt][nt], 0, 0, 0);
        }
        __syncthreads();
    }

    #pragma unroll
    for (int mt = 0; mt < 4; ++mt) {
        #pragma unroll
        for (int nt = 0; nt < 2; ++nt) {
            int col = n0 + wn * 32 + nt * 16 + cl;
            float bb = bias[col];
            #pragma unroll
            for (int rg = 0; rg < 4; ++rg) {
                int row = m0 + wm * 64 + mt * 16 + cq * 4 + rg;
                float v = acc[mt][nt][rg] + bb;
                if (EPI & 1) v = fmaxf(v, 0.f);
                if (EPI & 4) v += pe[(row & 127) * 384 + col];
                if (EPI & 2) v += resid[(size_t)row * N + col];
                if (EPI & 8) outF[(size_t)row * N + col] = v;
                if (EPI & 16) outB[(size_t)row * N + col] = f2bf(v);
            }
        }
    }
}

// ---------------- bf16 MFMA GEMM (wide-N): BM=128, BN=128, BK=32 dbuf ------
template <int EPI>
__global__ __launch_bounds__(256) void gemm_bf16_wide(
    const short* __restrict__ A, const short* __restrict__ Bt,
    const float* __restrict__ bias, float* __restrict__ outF,
    short* __restrict__ outB, int M, int N, int K)
{
    __shared__ short As[2][128 * 32];
    __shared__ short Bs[2][128 * 32];
    int tid = threadIdx.x;
    int w = tid >> 6, lane = tid & 63;
    int wm = w >> 1, wn = w & 1;
    int m0 = blockIdx.y * 128, n0 = blockIdx.x * 128;

    int rl = lane >> 2, sl = lane & 3;
    int cb = sl ^ (rl & 3) ^ ((rl >> 2) & 3);
    const short* aptr[2];
    const short* bptr[2];
    int srow[2];
    #pragma unroll
    for (int l = 0; l < 2; ++l) {
        srow[l] = w * 32 + l * 16;
        aptr[l] = A + (size_t)(m0 + srow[l] + rl) * K + cb * 8;
        bptr[l] = Bt + (size_t)(n0 + srow[l] + rl) * K + cb * 8;
    }

    int cq = lane >> 4, cl = lane & 15;
    f32x4 acc[4][4];
    #pragma unroll
    for (int mt = 0; mt < 4; ++mt)
        #pragma unroll
        for (int nt = 0; nt < 4; ++nt)
            acc[mt][nt] = (f32x4){0.f, 0.f, 0.f, 0.f};

    #pragma unroll
    for (int l = 0; l < 2; ++l) {
        gload_lds16(aptr[l], &As[0][srow[l] * 32]);
        gload_lds16(bptr[l], &Bs[0][srow[l] * 32]);
        aptr[l] += 32; bptr[l] += 32;
    }
    __syncthreads();

    int nk = K >> 5;
    for (int k = 0; k < nk; ++k) {
        int cur = k & 1;
        if (k + 1 < nk) {
            #pragma unroll
            for (int l = 0; l < 2; ++l) {
                gload_lds16(aptr[l], &As[cur ^ 1][srow[l] * 32]);
                gload_lds16(bptr[l], &Bs[cur ^ 1][srow[l] * 32]);
                aptr[l] += 32; bptr[l] += 32;
            }
        }
        bf16x8 afr[4], bfr[4];
        #pragma unroll
        for (int mt = 0; mt < 4; ++mt) {
            int r = wm * 64 + mt * 16 + cl;
            int slot = cq ^ (r & 3) ^ ((r >> 2) & 3);
            afr[mt] = *(const bf16x8*)&As[cur][r * 32 + slot * 8];
        }
        #pragma unroll
        for (int nt = 0; nt < 4; ++nt) {
            int r = wn * 64 + nt * 16 + cl;
            int slot = cq ^ (r & 3) ^ ((r >> 2) & 3);
            bfr[nt] = *(const bf16x8*)&Bs[cur][r * 32 + slot * 8];
        }
        #pragma unroll
        for (int mt = 0; mt < 4; ++mt)
            #pragma unroll
            for (int nt = 0; nt < 4; ++nt)
                acc[mt][nt] = __builtin_amdgcn_mfma_f32_16x16x32_bf16(
                    afr[mt], bfr[nt], acc[mt][nt], 0, 0, 0);
        __syncthreads();
    }

    #pragma unroll
    for (int mt = 0; mt < 4; ++mt) {
        #pragma unroll
        for (int nt = 0; nt < 4; ++nt) {
            int col = n0 + wn * 64 + nt * 16 + cl;
            float bb = bias[col];
            #pragma unroll
            for (int rg = 0; rg < 4; ++rg) {
                int row = m0 + wm * 64 + mt * 16 + cq * 4 + rg;
                float v = acc[mt][nt][rg] + bb;
                if (EPI & 1) v = fmaxf(v, 0.f);
                if (EPI & 8) outF[(size_t)row * N + col] = v;
                if (EPI & 16) outB[(size_t)row * N + col] = f2bf(v);
            }
        }
    }
}

// ---------------- fused GEMM + bias + residual + LayerNorm -----------------
// R24: BM=32, BN=384, BK=64, 512 threads, grid 256, double-buffered LDS.
__global__ __launch_bounds__(512) void gemm_ln(
    const short* __restrict__ A, const short* __restrict__ Bt,
    const float* __restrict__ bias, const float* resid,
    const float* __restrict__ g, const float* __restrict__ be,
    float* t, short* __restrict__ tb, int K)
{
    __shared__ __align__(16) char smem[106496];
    short* As0 = (short*)smem;                 // [2][32*64]  = 8 KB
    short* Bs0 = (short*)(smem + 8192);        // [2][384*64] = 96 KB

    int tid = threadIdx.x;
    int w = tid >> 6, lane = tid & 63;
    int m0 = blockIdx.x * 32;
    int rl = lane >> 3, sl = lane & 7;
    int cb = sl ^ rl;

    const short* aptr = A + (size_t)(m0 + (w & 3) * 8 + rl) * K + cb * 8;
    const short* bptr[6];
    #pragma unroll
    for (int l = 0; l < 6; ++l)
        bptr[l] = Bt + (size_t)(w * 48 + l * 8 + rl) * K + cb * 8;

    int cq = lane >> 4, cl = lane & 15;
    f32x4 acc[2][3];
    #pragma unroll
    for (int mt = 0; mt < 2; ++mt)
        #pragma unroll
        for (int nt = 0; nt < 3; ++nt)
            acc[mt][nt] = (f32x4){0.f, 0.f, 0.f, 0.f};

    if (w < 4) { gload_lds16(aptr, &As0[(w * 8) * 64]); aptr += 64; }
    #pragma unroll
    for (int l = 0; l < 6; ++l) {
        gload_lds16(bptr[l], &Bs0[(w * 48 + l * 8) * 64]);
        bptr[l] += 64;
    }
    __syncthreads();

    int nk = K >> 6;
    for (int k = 0; k < nk; ++k) {
        int cur = k & 1;
        if (k + 1 < nk) {
            if (w < 4) { gload_lds16(aptr, &As0[(cur ^ 1) * 2048 + (w * 8) * 64]); aptr += 64; }
            #pragma unroll
            for (int l = 0; l < 6; ++l) {
                gload_lds16(bptr[l], &Bs0[(cur ^ 1) * 24576 + (w * 48 + l * 8) * 64]);
                bptr[l] += 64;
            }
        }
        const short* As = As0 + cur * 2048;
        const short* Bs = Bs0 + cur * 24576;
        #pragma unroll
        for (int s = 0; s < 2; ++s) {
            bf16x8 afr[2], bfr[3];
            #pragma unroll
            for (int mt = 0; mt < 2; ++mt) {
                int r = mt * 16 + cl;
                int slot = (s * 4 + cq) ^ (r & 7);
                afr[mt] = *(const bf16x8*)&As[r * 64 + slot * 8];
            }
            #pragma unroll
            for (int nt = 0; nt < 3; ++nt) {
                int r = w * 48 + nt * 16 + cl;
                int slot = (s * 4 + cq) ^ (r & 7);
                bfr[nt] = *(const bf16x8*)&Bs[r * 64 + slot * 8];
            }
            #pragma unroll
            for (int mt = 0; mt < 2; ++mt)
                #pragma unroll
                for (int nt = 0; nt < 3; ++nt)
                    acc[mt][nt] = __builtin_amdgcn_mfma_f32_16x16x32_bf16(
                        afr[mt], bfr[nt], acc[mt][nt], 0, 0, 0);
        }
        __syncthreads();
    }

    float* yb = (float*)smem;
    #pragma unroll
    for (int mt = 0; mt < 2; ++mt) {
        #pragma unroll
        for (int nt = 0; nt < 3; ++nt) {
            int col = w * 48 + nt * 16 + cl;
            float bb = bias[col];
            #pragma unroll
            for (int rg = 0; rg < 4; ++rg) {
                int rloc = mt * 16 + cq * 4 + rg;
                yb[rloc * 388 + col] =
                    acc[mt][nt][rg] + bb + resid[(size_t)(m0 + rloc) * 384 + col];
            }
        }
    }
    __syncthreads();

    int rloc = tid >> 4, sub = tid & 15;
    f32x4 vals[6];
    float s = 0.f, s2 = 0.f;
    #pragma unroll
    for (int m = 0; m < 6; ++m) {
        f32x4 vv = *(const f32x4*)&yb[rloc * 388 + m * 64 + sub * 4];
        vals[m] = vv;
        #pragma unroll
        for (int j = 0; j < 4; ++j) {
            s += vv[j];
            s2 = fmaf(vv[j], vv[j], s2);
        }
    }
    s += __shfl_xor(s, 1, 64);  s2 += __shfl_xor(s2, 1, 64);
    s += __shfl_xor(s, 2, 64);  s2 += __shfl_xor(s2, 2, 64);
    s += __shfl_xor(s, 4, 64);  s2 += __shfl_xor(s2, 4, 64);
    s += __shfl_xor(s, 8, 64);  s2 += __shfl_xor(s2, 8, 64);
    float mean = s * (1.f / 384.f);
    float var = s2 * (1.f / 384.f) - mean * mean;
    float inv = rsqrtf(var + 1e-5f);

    size_t ro = (size_t)(m0 + rloc) * 384;
    #pragma unroll
    for (int m = 0; m < 6; ++m) {
        int c0 = m * 64 + sub * 4;
        f32x4 gg = *(const f32x4*)&g[c0];
        f32x4 bb = *(const f32x4*)&be[c0];
        f32x4 ov;
        s16x4 ob2;
        #pragma unroll
        for (int j = 0; j < 4; ++j) {
            float v = (vals[m][j] - mean) * inv * gg[j] + bb[j];
            ov[j] = v;
            ob2[j] = f2bf(v);
        }
        *(f32x4*)&t[ro + c0] = ov;
        *(s16x4*)&tb[ro + c0] = ob2;
    }
}

// ---------------- fused qkv-GEMM + attention per (n,h) ---------------------
__global__ __launch_bounds__(256) void qkvattn_kernel(
    const short* __restrict__ A, const short* __restrict__ Bt,
    const float* __restrict__ bias, short* __restrict__ o)
{
    __shared__ __align__(16) char smem[76544];
    short* As0 = (short*)smem;                 // [2][128*64]
    short* Bs0 = (short*)(smem + 32768);       // [2][144*64]
    short* Qs  = (short*)smem;                 // [128][56]
    short* Ks  = (short*)(smem + 14336);       // [128][56]
    short* Vt  = (short*)(smem + 28672);       // [48][136]
    short* P   = (short*)(smem + 41728);       // [4][32][136]

    int tid = threadIdx.x;
    int w = tid >> 6, lane = tid & 63;
    int cq = lane >> 4, cl = lane & 15;
    int n = blockIdx.x >> 3, h = blockIdx.x & 7;
    int m0 = n * 128;

    // ---- phase 1: qkv GEMM ----
    int rl = lane >> 3, sl = lane & 7;
    int cb = sl ^ rl;
    const short* aptr[4];
    int arow[4];
    #pragma unroll
    for (int l = 0; l < 4; ++l) {
        arow[l] = l * 32 + w * 8;
        aptr[l] = A + (size_t)(m0 + arow[l] + rl) * 384 + cb * 8;
    }
    const short* bptr[5];
    int brow[5];
    #pragma unroll
    for (int l = 0; l < 5; ++l) {
        brow[l] = (l < 4) ? (l * 32 + w * 8) : (128 + w * 8);
        int r = brow[l] + rl;
        int g0 = (r >= 96) ? 2 : ((r >= 48) ? 1 : 0);
        int loc = r - g0 * 48;
        bptr[l] = Bt + (size_t)(g0 * 384 + h * 48 + loc) * 384 + cb * 8;
    }

    f32x4 acc[2][9];
    #pragma unroll
    for (int mt = 0; mt < 2; ++mt)
        #pragma unroll
        for (int nt = 0; nt < 9; ++nt)
            acc[mt][nt] = (f32x4){0.f, 0.f, 0.f, 0.f};

    #pragma unroll
    for (int l = 0; l < 4; ++l) { gload_lds16(aptr[l], &As0[arow[l] * 64]); aptr[l] += 64; }
    #pragma unroll
    for (int l = 0; l < 5; ++l) {
        if (l < 4 || w < 2) { gload_lds16(bptr[l], &Bs0[brow[l] * 64]); }
        bptr[l] += 64;
    }
    __syncthreads();

    for (int k = 0; k < 6; ++k) {
        int cur = k & 1;
        if (k + 1 < 6) {
            #pragma unroll
            for (int l = 0; l < 4; ++l) {
                gload_lds16(aptr[l], &As0[(cur ^ 1) * 8192 + arow[l] * 64]);
                aptr[l] += 64;
            }
            #pragma unroll
            for (int l = 0; l < 5; ++l) {
                if (l < 4 || w < 2)
                    gload_lds16(bptr[l], &Bs0[(cur ^ 1) * 9216 + brow[l] * 64]);
                bptr[l] += 64;
            }
        }
        const short* Asb = As0 + cur * 8192;
        const short* Bsb = Bs0 + cur * 9216;
        #pragma unroll
        for (int s = 0; s < 2; ++s) {
            bf16x8 afr[2], bfr[9];
            #pragma unroll
            for (int mt = 0; mt < 2; ++mt) {
                int r = w * 32 + mt * 16 + cl;
                int slot = (s * 4 + cq) ^ (r & 7);
                afr[mt] = *(const bf16x8*)&Asb[r * 64 + slot * 8];
            }
            #pragma unroll
            for (int nt = 0; nt < 9; ++nt) {
                int r = nt * 16 + cl;
                int slot = (s * 4 + cq) ^ (r & 7);
                bfr[nt] = *(const bf16x8*)&Bsb[r * 64 + slot * 8];
            }
            #pragma unroll
            for (int mt = 0; mt < 2; ++mt)
                #pragma unroll
                for (int nt = 0; nt < 9; ++nt)
                    acc[mt][nt] = __builtin_amdgcn_mfma_f32_16x16x32_bf16(
                        afr[mt], bfr[nt], acc[mt][nt], 0, 0, 0);
        }
        __syncthreads();
    }

    // ---- epilogue: +bias, bf16 -> Qs/Ks (row-major) and Vt (transposed) ----
    const float* bh = bias + h * 48;
    #pragma unroll
    for (int mt = 0; mt < 2; ++mt) {
        #pragma unroll
        for (int nt = 0; nt < 9; ++nt) {
            int grp = nt / 3;
            int col = (nt - grp * 3) * 16 + cl;     // 0..47 within group
            float bb = bh[grp * 384 + col];
            if (grp == 2) {
                int row0 = w * 32 + mt * 16 + cq * 4;
                s16x4 pv;
                #pragma unroll
                for (int rg = 0; rg < 4; ++rg) pv[rg] = f2bf(acc[mt][nt][rg] + bb);
                *(s16x4*)&Vt[col * 136 + row0] = pv;
            } else {
                short* dst = (grp == 0) ? Qs : Ks;
                #pragma unroll
                for (int rg = 0; rg < 4; ++rg) {
                    int row = w * 32 + mt * 16 + cq * 4 + rg;
                    dst[row * 56 + col] = f2bf(acc[mt][nt][rg] + bb);
                }
            }
        }
    }
    __syncthreads();   // Qs/Ks/Vt ready for all waves

    // ---- phase 2: attention (R23 structure, LDS sources) ----
    const bf16x8 zf = (bf16x8){0, 0, 0, 0, 0, 0, 0, 0};
    bf16x8 qf[2][2];
    #pragma unroll
    for (int mt = 0; mt < 2; ++mt) {
        int r = w * 32 + mt * 16 + cl;
        qf[mt][0] = *(const bf16x8*)&Qs[r * 56 + cq * 8];
        qf[mt][1] = (cq < 2) ? *(const bf16x8*)&Qs[r * 56 + 32 + cq * 8] : zf;
    }

    f32x4 sacc[2][8];
    #pragma unroll
    for (int mt = 0; mt < 2; ++mt)
        #pragma unroll
        for (int kt = 0; kt < 8; ++kt)
            sacc[mt][kt] = (f32x4){0.f, 0.f, 0.f, 0.f};

    #pragma unroll
    for (int kt = 0; kt < 8; ++kt) {
        int r = kt * 16 + cl;
        bf16x8 kf0 = *(const bf16x8*)&Ks[r * 56 + cq * 8];
        bf16x8 kf1 = (cq < 2) ? *(const bf16x8*)&Ks[r * 56 + 32 + cq * 8] : zf;
        #pragma unroll
        for (int mt = 0; mt < 2; ++mt) {
            sacc[mt][kt] = __builtin_amdgcn_mfma_f32_16x16x32_bf16(
                qf[mt][0], kf0, sacc[mt][kt], 0, 0, 0);
            sacc[mt][kt] = __builtin_amdgcn_mfma_f32_16x16x32_bf16(
                qf[mt][1], kf1, sacc[mt][kt], 0, 0, 0);
        }
    }

    const float temp = 0.14433756729740643f;  // 1/sqrt(48)
    short* Pw = P + w * 4352;
    float denom[2][4];
    #pragma unroll
    for (int mt = 0; mt < 2; ++mt) {
        #pragma unroll
        for (int rg = 0; rg < 4; ++rg) {
            float mx = sacc[mt][0][rg];
            #pragma unroll
            for (int kt = 1; kt < 8; ++kt) mx = fmaxf(mx, sacc[mt][kt][rg]);
            mx = fmaxf(mx, __shfl_xor(mx, 1, 64));
            mx = fmaxf(mx, __shfl_xor(mx, 2, 64));
            mx = fmaxf(mx, __shfl_xor(mx, 4, 64));
            mx = fmaxf(mx, __shfl_xor(mx, 8, 64));
            int row = mt * 16 + cq * 4 + rg;
            float se = 0.f;
            #pragma unroll
            for (int kt = 0; kt < 8; ++kt) {
                float p = __expf(temp * (sacc[mt][kt][rg] - mx));
                se += p;
                Pw[row * 136 + kt * 16 + cl] = f2bf(p);
            }
            se += __shfl_xor(se, 1, 64);
            se += __shfl_xor(se, 2, 64);
            se += __shfl_xor(se, 4, 64);
            se += __shfl_xor(se, 8, 64);
            denom[mt][rg] = se;
        }
    }

    f32x4 oacc[2][3];
    #pragma unroll
    for (int mt = 0; mt < 2; ++mt)
        #pragma unroll
        for (int nt = 0; nt < 3; ++nt)
            oacc[mt][nt] = (f32x4){0.f, 0.f, 0.f, 0.f};

    #pragma unroll
    for (int ks = 0; ks < 4; ++ks) {
        bf16x8 paf[2];
        #pragma unroll
        for (int mt = 0; mt < 2; ++mt)
            paf[mt] = *(const bf16x8*)&Pw[(mt * 16 + cl) * 136 + ks * 32 + cq * 8];
        #pragma unroll
        for (int nt = 0; nt < 3; ++nt) {
            bf16x8 vf = *(const bf16x8*)&Vt[(nt * 16 + cl) * 136 + ks * 32 + cq * 8];
            #pragma unroll
            for (int mt = 0; mt < 2; ++mt)
                oacc[mt][nt] = __builtin_amdgcn_mfma_f32_16x16x32_bf16(
                    paf[mt], vf, oacc[mt][nt], 0, 0, 0);
        }
    }

    #pragma unroll
    for (int mt = 0; mt < 2; ++mt) {
        #pragma unroll
        for (int rg = 0; rg < 4; ++rg) {
            float inv = 1.f / denom[mt][rg];
            int qrow = w * 32 + mt * 16 + cq * 4 + rg;
            short* op = o + ((size_t)n * 128 + qrow) * 384 + h * 48;
            #pragma unroll
            for (int nt = 0; nt < 3; ++nt)
                op[nt * 16 + cl] = f2bf(oacc[mt][nt][rg] * inv);
        }
    }
}

// ---------------- classifier head ------------------------------------------
__global__ __launch_bounds__(384) void head_kernel(
    const float* __restrict__ t, const float* __restrict__ cls_w,
    const float* __restrict__ cls_b, float* __restrict__ out)
{
    int n = blockIdx.x, d = threadIdx.x;
    float s = 0.f;
    for (int l = 0; l < 128; ++l) s += t[((size_t)n * 128 + l) * 384 + d];
    float p = s * (1.f / 128.f) * cls_w[d];
    #pragma unroll
    for (int off = 32; off > 0; off >>= 1) p += __shfl_xor(p, off, 64);
    __shared__ float red[6];
    if ((threadIdx.x & 63) == 0) red[threadIdx.x >> 6] = p;
    __syncthreads();
    if (threadIdx.x == 0) {
        float tot = red[0] + red[1] + red[2] + red[3] + red[4] + red[5];
        out[n] = tot + cls_b[0];
    }
}

// ---------------------------------------------------------------------------
extern "C" void kernel_launch(void* const* d_in, const int* in_sizes, int n_in,
                              void* d_out, int out_size, void* d_ws, size_t ws_size,
                              hipStream_t stream) {
    (void)n_in; (void)out_size; (void)ws_size;
    const float* x   = (const float*)d_in[0];
    const float* cw0 = (const float*)d_in[1];
    const float* cb0 = (const float*)d_in[2];
    const float* cw1 = (const float*)d_in[3];
    const float* cb1 = (const float*)d_in[4];
    const float* cw2 = (const float*)d_in[5];
    const float* cb2 = (const float*)d_in[6];
    const float* ew  = (const float*)d_in[7];
    const float* eb  = (const float*)d_in[8];
    bool dict_order = (in_sizes[10] == 589824);
    const float *Wq, *Wk, *Wv, *Wo, *W1, *W2, *bq, *bk, *bv, *bo, *b1, *b2;
    if (dict_order) {
        Wq = (const float*)d_in[9];  Wk = (const float*)d_in[10];
        Wv = (const float*)d_in[11]; Wo = (const float*)d_in[12];
        W1 = (const float*)d_in[13]; W2 = (const float*)d_in[14];
        bq = (const float*)d_in[15]; bk = (const float*)d_in[16];
        bv = (const float*)d_in[17]; bo = (const float*)d_in[18];
        b1 = (const float*)d_in[19]; b2 = (const float*)d_in[20];
    } else {
        Wq = (const float*)d_in[9];  bq = (const float*)d_in[10];
        Wk = (const float*)d_in[11]; bk = (const float*)d_in[12];
        Wv = (const float*)d_in[13]; bv = (const float*)d_in[14];
        Wo = (const float*)d_in[15]; bo = (const float*)d_in[16];
        W1 = (const float*)d_in[17]; b1 = (const float*)d_in[18];
        W2 = (const float*)d_in[19]; b2 = (const float*)d_in[20];
    }
    const float* g1  = (const float*)d_in[21];
    const float* be1 = (const float*)d_in[22];
    const float* g2  = (const float*)d_in[23];
    const float* be2 = (const float*)d_in[24];
    const float* clw = (const float*)d_in[25];
    const float* clb = (const float*)d_in[26];

    // ---- workspace layout (bytes) ----
    char* wp = (char*)d_ws;
    float* pe    = (float*)wp; wp += 196608;      // 128*384 f32
    short* featb = (short*)wp; wp += 33554432;    // 8192*2048 bf16 (reused as FFN hidden)
    float* t     = (float*)wp; wp += 12582912;    // 8192*384 f32
    short* tb    = (short*)wp; wp += 6291456;     // 8192*384 bf16
    short* qkvb  = (short*)wp; wp += 18874368;    // (unused after R26)
    short* ob    = (short*)wp; wp += 6291456;     // 8192*384 bf16 (attn out)
    short* ewT   = (short*)wp; wp += 1572864;     // 384 x 2048
    short* WqkvT = (short*)wp; wp += 3538944;     // 4 x 1152 x 384
    short* WoT   = (short*)wp; wp += 1179648;     // 4 x 384 x 384
    short* W1T   = (short*)wp; wp += 4718592;     // 4 x 1536 x 384
    short* W2T   = (short*)wp; wp += 4718592;     // 4 x 384 x 1536
    float* bqkv  = (float*)wp; wp += 18432;       // 4 x 1152 f32
    short* w2T   = (short*)wp; wp += 16384;       // 64 x 128 bf16 (conv2)
    short* w1m   = (short*)wp; wp += 2048;        // 2 x 16 x 32 bf16 (conv1)
    short* hb    = featb;                         // FFN hidden 8192*1536 bf16
    (void)qkvb;

    const int ROWS = 8192;

    prep_kernel<<<7926, 256, 0, stream>>>(ew, Wq, Wk, Wv, Wo, W1, W2,
                                          bq, bk, bv, cw2, cw1,
                                          ewT, WqkvT, WoT, W1T, W2T,
                                          pe, bqkv, w2T, w1m);
    cnn_kernel<<<4096, 128, 0, stream>>>(x, cw0, cb0, w1m, cb1, w2T, cb2, featb);

    // t/tb = relu(feat @ ew + eb) + pe
    gemm_bf16<29><<<dim3(6, 64), 256, 0, stream>>>(featb, ewT, eb, nullptr, pe,
                                                   t, tb, ROWS, 384, 2048);
    for (int i = 0; i < 4; ++i) {
        const short* WqkvTi = WqkvT + (size_t)i * 442368;
        const short* WoTi = WoT + (size_t)i * 147456;
        const short* W1Ti = W1T + (size_t)i * 589824;
        const short* W2Ti = W2T + (size_t)i * 589824;
        // ob = attn(qkv(tb)) fused
        qkvattn_kernel<<<512, 256, 0, stream>>>(tb, WqkvTi, bqkv + i * 1152, ob);
        // t/tb = LN(o @ Wo + bo + t)
        gemm_ln<<<256, 512, 0, stream>>>(ob, WoTi, bo + i * 384, t,
            g1 + i * 384, be1 + i * 384, t, tb, 384);
        // hidden = relu(t @ W1 + b1)
        gemm_bf16_wide<17><<<dim3(12, 64), 256, 0, stream>>>(tb, W1Ti,
            b1 + i * 1536, nullptr, hb, ROWS, 1536, 384);
        // t/tb = LN(hidden @ W2 + b2 + t)
        gemm_ln<<<256, 512, 0, stream>>>(hb, W2Ti, b2 + i * 384, t,
            g2 + i * 384, be2 + i * 384, t, tb, 1536);
    }
    head_kernel<<<64, 384, 0, stream>>>(t, clw, clb, (float*)d_out);
}

// Round 17
// 562.436 us; speedup vs baseline: 1.0096x; 1.0096x over previous
//
#include <hip/hip_runtime.h>
#include <math.h>

// ---------------------------------------------------------------------------
// N=64, L=128, W=256, D=384, H=8, E=48, NL=4, DFF=1536, rows = N*L = 8192
// GEMMs: bf16 MFMA 16x16x32, A [M][K] bf16 row-major, Bt [N][K] bf16.
// R34 = resubmit of R33 (= R31, measured session best 562.8us); R33's
// bench failed with GPUAcquisitionTimeout (infra, no data).
// cnn: ONE WAVE per window (grid 8192 x 64 thr, zero barriers, conv1 via
// MFMA paired-shift). Ledger: cnn at per-wave latency floor (R30/R31/R32);
// transformer kernels within ~1.5x of L2/MFMA floors (R24/R27/R28);
// dispatch overhead minimized (R25/R26). Expect ~563us -> plateau.
// ---------------------------------------------------------------------------

typedef float f32x4 __attribute__((ext_vector_type(4)));
typedef short bf16x8 __attribute__((ext_vector_type(8)));
typedef short s16x4 __attribute__((ext_vector_type(4)));

__device__ __forceinline__ short f2bf(float f) {
    union { float f; unsigned u; } c; c.f = f;
    unsigned r = (c.u + 0x7FFFu + ((c.u >> 16) & 1u)) >> 16;
    return (short)r;
}
__device__ __forceinline__ float bf2f(short s) {
    union { unsigned u; float f; } c;
    c.u = ((unsigned)(unsigned short)s) << 16;
    return c.f;
}

__device__ __forceinline__ void gload_lds16(const void* g, void* l) {
    __builtin_amdgcn_global_load_lds(
        (const __attribute__((address_space(1))) unsigned int*)g,
        (__attribute__((address_space(3))) unsigned int*)l,
        16, 0, 0);
}

// ---------------- merged prep: weight cvt + pe + biascat + w2cvt + w1cvt ---
__global__ __launch_bounds__(256) void prep_kernel(
    const float* __restrict__ ew,
    const float* __restrict__ Wq, const float* __restrict__ Wk,
    const float* __restrict__ Wv, const float* __restrict__ Wo,
    const float* __restrict__ W1, const float* __restrict__ W2,
    const float* __restrict__ bq, const float* __restrict__ bk,
    const float* __restrict__ bv, const float* __restrict__ w2,
    const float* __restrict__ w1c,
    short* __restrict__ ewT, short* __restrict__ WqkvT,
    short* __restrict__ WoT, short* __restrict__ W1T,
    short* __restrict__ W2T, float* __restrict__ pe,
    float* __restrict__ bqkv, short* __restrict__ w2T,
    short* __restrict__ w1m)
{
    __shared__ float tile[32][33];
    int id = blockIdx.x;
    int tid = threadIdx.x;
    int tx = tid & 31, ty = tid >> 5;

    const float* Wp;
    short* Wtp;
    int K, N, kb, nb;

    if (id < 768) {
        K = 2048; N = 384;
        kb = (id & 63) * 32; nb = (id >> 6) * 32;
        Wp = ew; Wtp = ewT;
    } else if (id < 2496) {
        int t = id - 768;
        int kbi = t % 12, nbi = (t / 12) % 12, z = t / 144;
        int layer = z / 3, which = z - layer * 3;
        K = 384; N = 384; kb = kbi * 32; nb = nbi * 32;
        Wp = (which == 0 ? Wq : (which == 1 ? Wk : Wv)) + (size_t)layer * 147456;
        Wtp = WqkvT + (size_t)layer * 442368 + (size_t)which * 147456;
    } else if (id < 3072) {
        int t = id - 2496;
        int kbi = t % 12, nbi = (t / 12) % 12, z = t / 144;
        K = 384; N = 384; kb = kbi * 32; nb = nbi * 32;
        Wp = Wo + (size_t)z * 147456; Wtp = WoT + (size_t)z * 147456;
    } else if (id < 5376) {
        int t = id - 3072;
        int kbi = t % 12, nbi = (t / 12) % 48, z = t / 576;
        K = 384; N = 1536; kb = kbi * 32; nb = nbi * 32;
        Wp = W1 + (size_t)z * 589824; Wtp = W1T + (size_t)z * 589824;
    } else if (id < 7680) {
        int t = id - 5376;
        int kbi = t % 48, nbi = (t / 48) % 12, z = t / 576;
        K = 1536; N = 384; kb = kbi * 32; nb = nbi * 32;
        Wp = W2 + (size_t)z * 589824; Wtp = W2T + (size_t)z * 589824;
    } else if (id < 7872) {
        int idx = (id - 7680) * 256 + tid;
        int l = idx / 384, d = idx - l * 384;
        int i2 = d >> 1;
        float ang = (float)l * expf(-(2.0f * (float)i2 / 384.0f) * 9.210340371976184f);
        pe[idx] = (d & 1) ? cosf(ang) : sinf(ang);
        return;
    } else if (id < 7890) {
        int idx = (id - 7872) * 256 + tid;
        int l = idx / 1152, j3 = idx - l * 1152;
        int which = j3 / 384, j = j3 - which * 384;
        const float* b = (which == 0 ? bq : (which == 1 ? bk : bv));
        bqkv[idx] = b[l * 384 + j];
        return;
    } else if (id < 7922) {
        int idx = (id - 7890) * 256 + tid;
        int c = idx >> 7, r = idx & 127;
        int pr = r >> 5, q = (r >> 3) & 3, j = r & 7;
        int ci = (q & 1) * 8 + j;
        int sft = 2 * pr + (q >> 1);
        w2T[idx] = (sft < 7) ? f2bf(w2[c * 112 + ci * 7 + sft]) : (short)0;
        return;
    } else {
        int idx = (id - 7922) * 256 + tid;   // 0..1023
        int t = idx >> 9, ch = (idx >> 5) & 15, k = idx & 31;
        int q = k >> 3, j = k & 7;
        int s = t * 4 + q;
        w1m[idx] = (j < 4 && s < 7) ? f2bf(w1c[(ch * 4 + j) * 7 + s]) : (short)0;
        return;
    }

    #pragma unroll
    for (int r = ty; r < 32; r += 8)
        tile[r][tx] = Wp[(size_t)(kb + r) * N + nb + tx];
    __syncthreads();
    #pragma unroll
    for (int r = ty; r < 32; r += 8)
        Wtp[(size_t)(nb + r) * K + kb + tx] = f2bf(tile[tx][r]);
}

// ---------------- fused CNN window encoder: 1 WAVE per window, 0 barriers --
// LDS layout (6688 B):
//   [0    .. 1056)  xs[264] f32  (x at idx j+4, zeros [0..3],[260..263])
//   [1056 .. 3216)  p0T8[135][8] bf16 (row = pre-pool pos + 3; slots
//                   0..3 = ci, 4..7 = 0; rows 0..2, 131..134 zero)
//   [3216 .. 6672)  p1T[72][24] bf16 (row = pos+3, pad rows zeroed)
__global__ __launch_bounds__(64) void cnn_kernel(
    const float* __restrict__ x,
    const float* __restrict__ w0, const float* __restrict__ b0,
    const short* __restrict__ w1m, const float* __restrict__ b1,
    const short* __restrict__ w2T, const float* __restrict__ b2,
    short* __restrict__ feat)
{
    __shared__ __align__(16) char smem[6688];
    float* xs   = (float*)smem;                   // [264]
    short* p0T8 = (short*)(smem + 1056);          // [135][8]
    short* p1T  = (short*)(smem + 3216);          // [72][24]

    int lane = threadIdx.x;
    size_t win = blockIdx.x;
    int cq = lane >> 4, cl = lane & 15;

    // ---- setup: w0 to regs, xs fill, zero p0T8 ----
    int ca = lane & 3;
    float w0r[7];
    float b0r = b0[ca];
    #pragma unroll
    for (int k = 0; k < 7; ++k) w0r[k] = w0[ca * 7 + k];

    {
        f32x4 v = *(const f32x4*)(x + win * 256 + lane * 4);
        *(f32x4*)&xs[4 + lane * 4] = v;
        if (lane < 2) *(f32x4*)&xs[lane * 260] = (f32x4){0.f, 0.f, 0.f, 0.f};
    }
    {
        int* pz = (int*)p0T8;                     // 540 dwords
        #pragma unroll
        for (int i = 0; i < 9; ++i) {
            int idx = i * 64 + lane;
            if (idx < 540) pz[idx] = 0;
        }
    }

    // ---- stage A: conv0 + relu + pool2 -> p0T8 rows 3..130 ----
    {
        int pa = lane >> 2;
        #pragma unroll
        for (int t2 = 0; t2 < 8; ++t2) {
            int pp = t2 * 16 + pa;
            float rv[9];
            #pragma unroll
            for (int u = 0; u < 9; ++u) rv[u] = xs[2 * pp + u + 1];
            float a0 = b0r, a1 = b0r;
            #pragma unroll
            for (int k = 0; k < 7; ++k) {
                a0 = fmaf(w0r[k], rv[k], a0);
                a1 = fmaf(w0r[k], rv[k + 1], a1);
            }
            p0T8[(pp + 3) * 8 + ca] = f2bf(fmaxf(fmaxf(a0, a1), 0.f));
        }
    }

    // ---- stage B: conv1 via MFMA paired-shift + pool -> p1T ----
    {
        bf16x8 w1f0 = *(const bf16x8*)&w1m[cl * 32 + cq * 8];
        bf16x8 w1f1 = *(const bf16x8*)&w1m[512 + cl * 32 + cq * 8];
        f32x4 b1v = *(const f32x4*)&b1[cq * 4];
        #pragma unroll
        for (int pt = 0; pt < 8; ++pt) {
            f32x4 hacc = (f32x4){0.f, 0.f, 0.f, 0.f};
            bf16x8 bf0 = *(const bf16x8*)&p0T8[(pt * 16 + cl + cq) * 8];
            hacc = __builtin_amdgcn_mfma_f32_16x16x32_bf16(w1f0, bf0, hacc, 0, 0, 0);
            bf16x8 bf1 = *(const bf16x8*)&p0T8[(pt * 16 + cl + 4 + cq) * 8];
            hacc = __builtin_amdgcn_mfma_f32_16x16x32_bf16(w1f1, bf1, hacc, 0, 0, 0);
            #pragma unroll
            for (int rg = 0; rg < 4; ++rg) {
                float v = hacc[rg] + b1v[rg];
                float v2 = __shfl_xor(v, 1, 64);
                if ((cl & 1) == 0) {
                    int po = (pt * 16 + cl) >> 1;
                    p1T[(3 + po) * 24 + cq * 4 + rg] =
                        f2bf(fmaxf(fmaxf(v, v2), 0.f));
                }
            }
        }
    }
    // zero p1T pad rows: rows 0..2 (dwords 0..35), 67..71 (804..863)
    {
        int* pz = (int*)p1T;
        if (lane < 36) pz[lane] = 0;
        if (lane < 60) pz[804 + lane] = 0;
    }
    // NO barrier: everything below is wave-local (LDS ops ordered in-wave)

    // ---- stage C: conv2 as 4 paired-shift GEMMs, 2 pos-tiles x 4 ch-tiles -
    f32x4 acc[2][4];   // [pos tile pt][channel tile mt]
    #pragma unroll
    for (int pt = 0; pt < 2; ++pt)
        #pragma unroll
        for (int mt = 0; mt < 4; ++mt)
            acc[pt][mt] = (f32x4){0.f, 0.f, 0.f, 0.f};

    {
        const short* bpb0 = p1T + (cl + (cq >> 1)) * 24 + (cq & 1) * 8;
        const short* bpb1 = bpb0 + 16 * 24;
        #pragma unroll
        for (int pr = 0; pr < 4; ++pr) {
            bf16x8 bfr0 = *(const bf16x8*)&bpb0[pr * 48];
            bf16x8 bfr1 = *(const bf16x8*)&bpb1[pr * 48];
            #pragma unroll
            for (int mt = 0; mt < 4; ++mt) {
                bf16x8 af = *(const bf16x8*)&w2T[(mt * 16 + cl) * 128 +
                                                 pr * 32 + cq * 8];
                acc[0][mt] = __builtin_amdgcn_mfma_f32_16x16x32_bf16(
                    af, bfr0, acc[0][mt], 0, 0, 0);
                acc[1][mt] = __builtin_amdgcn_mfma_f32_16x16x32_bf16(
                    af, bfr1, acc[1][mt], 0, 0, 0);
            }
        }
    }

    // ---- epilogue: pool pairs via shfl, store bf16 ----
    short* fp = feat + win * 2048;
    #pragma unroll
    for (int pt = 0; pt < 2; ++pt) {
        int iev = (pt * 16 + cl) >> 1;
        #pragma unroll
        for (int mt = 0; mt < 4; ++mt) {
            #pragma unroll
            for (int rg = 0; rg < 4; ++rg) {
                float vv = acc[pt][mt][rg];
                float v2 = __shfl_xor(vv, 1, 64);
                if ((cl & 1) == 0) {
                    int c = mt * 16 + cq * 4 + rg;
                    float pv = fmaxf(fmaxf(vv, v2) + b2[c], 0.f);
                    fp[c * 32 + iev] = f2bf(pv);
                }
            }
        }
    }
}

// ---------------- bf16 MFMA GEMM (thin-N): BM=128, BN=64, double-buffered --
template <int EPI>
__global__ __launch_bounds__(256) void gemm_bf16(
    const short* __restrict__ A, const short* __restrict__ Bt,
    const float* __restrict__ bias, const float* __restrict__ resid,
    const float* __restrict__ pe, float* __restrict__ outF,
    short* __restrict__ outB, int M, int N, int K)
{
    __shared__ short As[2][128 * 64];
    __shared__ short Bs[2][64 * 64];
    int tid = threadIdx.x;
    int w = tid >> 6, lane = tid & 63;
    int wm = w >> 1, wn = w & 1;
    int m0 = blockIdx.y * 128, n0 = blockIdx.x * 64;

    int rl = lane >> 3, sl = lane & 7;
    int cb = sl ^ rl;
    const short* aptr[4];
    const short* bptr[2];
    int arow[4], brow[2];
    #pragma unroll
    for (int l = 0; l < 4; ++l) {
        arow[l] = l * 32 + w * 8;
        aptr[l] = A + (size_t)(m0 + arow[l] + rl) * K + cb * 8;
    }
    #pragma unroll
    for (int l = 0; l < 2; ++l) {
        brow[l] = l * 32 + w * 8;
        bptr[l] = Bt + (size_t)(n0 + brow[l] + rl) * K + cb * 8;
    }

    int cq = lane >> 4, cl = lane & 15;
    f32x4 acc[4][2];
    #pragma unroll
    for (int mt = 0; mt < 4; ++mt)
        #pragma unroll
        for (int nt = 0; nt < 2; ++nt)
            acc[mt][nt] = (f32x4){0.f, 0.f, 0.f, 0.f};

    #pragma unroll
    for (int l = 0; l < 4; ++l) { gload_lds16(aptr[l], &As[0][arow[l] * 64]); aptr[l] += 64; }
    #pragma unroll
    for (int l = 0; l < 2; ++l) { gload_lds16(bptr[l], &Bs[0][brow[l] * 64]); bptr[l] += 64; }
    __syncthreads();

    int nk = K >> 6;
    for (int k = 0; k < nk; ++k) {
        int cur = k & 1;
        if (k + 1 < nk) {
            #pragma unroll
            for (int l = 0; l < 4; ++l) { gload_lds16(aptr[l], &As[cur ^ 1][arow[l] * 64]); aptr[l] += 64; }
            #pragma unroll
            for (int l = 0; l < 2; ++l) { gload_lds16(bptr[l], &Bs[cur ^ 1][brow[l] * 64]); bptr[l] += 64; }
        }
        #pragma unroll
        for (int s = 0; s < 2; ++s) {
            bf16x8 afr[4], bfr[2];
            #pragma unroll
            for (int mt = 0; mt < 4; ++mt) {
                int r = wm * 64 + mt * 16 + cl;
                int slot = (s * 4 + cq) ^ (r & 7);
                afr[mt] = *(const bf16x8*)&As[cur][r * 64 + slot * 8];
            }
            #pragma unroll
            for (int nt = 0; nt < 2; ++nt) {
                int r = wn * 32 + nt * 16 + cl;
                int slot = (s * 4 + cq) ^ (r & 7);
                bfr[nt] = *(const bf16x8*)&Bs[cur][r * 64 + slot * 8];
            }
            #pragma unroll
            for (int mt = 0; mt < 4; ++mt)
                #pragma unroll
                for (int nt = 0; nt < 2; ++nt)
                    acc[mt][nt] = __builtin_amdgcn_mfma_f32_16x16x32_bf16(
                        afr[mt], bfr[nt], acc[mt][nt], 0, 0, 0);
        }
        __syncthreads();
    }

    #pragma unroll
    for (int mt = 0; mt < 4; ++mt) {
        #pragma unroll
        for (int nt = 0; nt < 2; ++nt) {
            int col = n0 + wn * 32 + nt * 16 + cl;
            float bb = bias[col];
            #pragma unroll
            for (int rg = 0; rg < 4; ++rg) {
                int row = m0 + wm * 64 + mt * 16 + cq * 4 + rg;
                float v = acc[mt][nt][rg] + bb;
                if (EPI & 1) v = fmaxf(v, 0.f);
                if (EPI & 4) v += pe[(row & 127) * 384 + col];
                if (EPI & 2) v += resid[(size_t)row * N + col];
                if (EPI & 8) outF[(size_t)row * N + col] = v;
                if (EPI & 16) outB[(size_t)row * N + col] = f2bf(v);
            }
        }
    }
}

// ---------------- bf16 MFMA GEMM (wide-N): BM=128, BN=128, BK=32 dbuf ------
template <int EPI>
__global__ __launch_bounds__(256) void gemm_bf16_wide(
    const short* __restrict__ A, const short* __restrict__ Bt,
    const float* __restrict__ bias, float* __restrict__ outF,
    short* __restrict__ outB, int M, int N, int K)
{
    __shared__ short As[2][128 * 32];
    __shared__ short Bs[2][128 * 32];
    int tid = threadIdx.x;
    int w = tid >> 6, lane = tid & 63;
    int wm = w >> 1, wn = w & 1;
    int m0 = blockIdx.y * 128, n0 = blockIdx.x * 128;

    int rl = lane >> 2, sl = lane & 3;
    int cb = sl ^ (rl & 3) ^ ((rl >> 2) & 3);
    const short* aptr[2];
    const short* bptr[2];
    int srow[2];
    #pragma unroll
    for (int l = 0; l < 2; ++l) {
        srow[l] = w * 32 + l * 16;
        aptr[l] = A + (size_t)(m0 + srow[l] + rl) * K + cb * 8;
        bptr[l] = Bt + (size_t)(n0 + srow[l] + rl) * K + cb * 8;
    }

    int cq = lane >> 4, cl = lane & 15;
    f32x4 acc[4][4];
    #pragma unroll
    for (int mt = 0; mt < 4; ++mt)
        #pragma unroll
        for (int nt = 0; nt < 4; ++nt)
            acc[mt][nt] = (f32x4){0.f, 0.f, 0.f, 0.f};

    #pragma unroll
    for (int l = 0; l < 2; ++l) {
        gload_lds16(aptr[l], &As[0][srow[l] * 32]);
        gload_lds16(bptr[l], &Bs[0][srow[l] * 32]);
        aptr[l] += 32; bptr[l] += 32;
    }
    __syncthreads();

    int nk = K >> 5;
    for (int k = 0; k < nk; ++k) {
        int cur = k & 1;
        if (k + 1 < nk) {
            #pragma unroll
            for (int l = 0; l < 2; ++l) {
                gload_lds16(aptr[l], &As[cur ^ 1][srow[l] * 32]);
                gload_lds16(bptr[l], &Bs[cur ^ 1][srow[l] * 32]);
                aptr[l] += 32; bptr[l] += 32;
            }
        }
        bf16x8 afr[4], bfr[4];
        #pragma unroll
        for (int mt = 0; mt < 4; ++mt) {
            int r = wm * 64 + mt * 16 + cl;
            int slot = cq ^ (r & 3) ^ ((r >> 2) & 3);
            afr[mt] = *(const bf16x8*)&As[cur][r * 32 + slot * 8];
        }
        #pragma unroll
        for (int nt = 0; nt < 4; ++nt) {
            int r = wn * 64 + nt * 16 + cl;
            int slot = cq ^ (r & 3) ^ ((r >> 2) & 3);
            bfr[nt] = *(const bf16x8*)&Bs[cur][r * 32 + slot * 8];
        }
        #pragma unroll
        for (int mt = 0; mt < 4; ++mt)
            #pragma unroll
            for (int nt = 0; nt < 4; ++nt)
                acc[mt][nt] = __builtin_amdgcn_mfma_f32_16x16x32_bf16(
                    afr[mt], bfr[nt], acc[mt][nt], 0, 0, 0);
        __syncthreads();
    }

    #pragma unroll
    for (int mt = 0; mt < 4; ++mt) {
        #pragma unroll
        for (int nt = 0; nt < 4; ++nt) {
            int col = n0 + wn * 64 + nt * 16 + cl;
            float bb = bias[col];
            #pragma unroll
            for (int rg = 0; rg < 4; ++rg) {
                int row = m0 + wm * 64 + mt * 16 + cq * 4 + rg;
                float v = acc[mt][nt][rg] + bb;
                if (EPI & 1) v = fmaxf(v, 0.f);
                if (EPI & 8) outF[(size_t)row * N + col] = v;
                if (EPI & 16) outB[(size_t)row * N + col] = f2bf(v);
            }
        }
    }
}

// ---------------- fused GEMM + bias + residual + LayerNorm -----------------
// R24: BM=32, BN=384, BK=64, 512 threads, grid 256, double-buffered LDS.
__global__ __launch_bounds__(512) void gemm_ln(
    const short* __restrict__ A, const short* __restrict__ Bt,
    const float* __restrict__ bias, const float* resid,
    const float* __restrict__ g, const float* __restrict__ be,
    float* t, short* __restrict__ tb, int K)
{
    __shared__ __align__(16) char smem[106496];
    short* As0 = (short*)smem;                 // [2][32*64]  = 8 KB
    short* Bs0 = (short*)(smem + 8192);        // [2][384*64] = 96 KB

    int tid = threadIdx.x;
    int w = tid >> 6, lane = tid & 63;
    int m0 = blockIdx.x * 32;
    int rl = lane >> 3, sl = lane & 7;
    int cb = sl ^ rl;

    const short* aptr = A + (size_t)(m0 + (w & 3) * 8 + rl) * K + cb * 8;
    const short* bptr[6];
    #pragma unroll
    for (int l = 0; l < 6; ++l)
        bptr[l] = Bt + (size_t)(w * 48 + l * 8 + rl) * K + cb * 8;

    int cq = lane >> 4, cl = lane & 15;
    f32x4 acc[2][3];
    #pragma unroll
    for (int mt = 0; mt < 2; ++mt)
        #pragma unroll
        for (int nt = 0; nt < 3; ++nt)
            acc[mt][nt] = (f32x4){0.f, 0.f, 0.f, 0.f};

    if (w < 4) { gload_lds16(aptr, &As0[(w * 8) * 64]); aptr += 64; }
    #pragma unroll
    for (int l = 0; l < 6; ++l) {
        gload_lds16(bptr[l], &Bs0[(w * 48 + l * 8) * 64]);
        bptr[l] += 64;
    }
    __syncthreads();

    int nk = K >> 6;
    for (int k = 0; k < nk; ++k) {
        int cur = k & 1;
        if (k + 1 < nk) {
            if (w < 4) { gload_lds16(aptr, &As0[(cur ^ 1) * 2048 + (w * 8) * 64]); aptr += 64; }
            #pragma unroll
            for (int l = 0; l < 6; ++l) {
                gload_lds16(bptr[l], &Bs0[(cur ^ 1) * 24576 + (w * 48 + l * 8) * 64]);
                bptr[l] += 64;
            }
        }
        const short* As = As0 + cur * 2048;
        const short* Bs = Bs0 + cur * 24576;
        #pragma unroll
        for (int s = 0; s < 2; ++s) {
            bf16x8 afr[2], bfr[3];
            #pragma unroll
            for (int mt = 0; mt < 2; ++mt) {
                int r = mt * 16 + cl;
                int slot = (s * 4 + cq) ^ (r & 7);
                afr[mt] = *(const bf16x8*)&As[r * 64 + slot * 8];
            }
            #pragma unroll
            for (int nt = 0; nt < 3; ++nt) {
                int r = w * 48 + nt * 16 + cl;
                int slot = (s * 4 + cq) ^ (r & 7);
                bfr[nt] = *(const bf16x8*)&Bs[r * 64 + slot * 8];
            }
            #pragma unroll
            for (int mt = 0; mt < 2; ++mt)
                #pragma unroll
                for (int nt = 0; nt < 3; ++nt)
                    acc[mt][nt] = __builtin_amdgcn_mfma_f32_16x16x32_bf16(
                        afr[mt], bfr[nt], acc[mt][nt], 0, 0, 0);
        }
        __syncthreads();
    }

    float* yb = (float*)smem;
    #pragma unroll
    for (int mt = 0; mt < 2; ++mt) {
        #pragma unroll
        for (int nt = 0; nt < 3; ++nt) {
            int col = w * 48 + nt * 16 + cl;
            float bb = bias[col];
            #pragma unroll
            for (int rg = 0; rg < 4; ++rg) {
                int rloc = mt * 16 + cq * 4 + rg;
                yb[rloc * 388 + col] =
                    acc[mt][nt][rg] + bb + resid[(size_t)(m0 + rloc) * 384 + col];
            }
        }
    }
    __syncthreads();

    int rloc = tid >> 4, sub = tid & 15;
    f32x4 vals[6];
    float s = 0.f, s2 = 0.f;
    #pragma unroll
    for (int m = 0; m < 6; ++m) {
        f32x4 vv = *(const f32x4*)&yb[rloc * 388 + m * 64 + sub * 4];
        vals[m] = vv;
        #pragma unroll
        for (int j = 0; j < 4; ++j) {
            s += vv[j];
            s2 = fmaf(vv[j], vv[j], s2);
        }
    }
    s += __shfl_xor(s, 1, 64);  s2 += __shfl_xor(s2, 1, 64);
    s += __shfl_xor(s, 2, 64);  s2 += __shfl_xor(s2, 2, 64);
    s += __shfl_xor(s, 4, 64);  s2 += __shfl_xor(s2, 4, 64);
    s += __shfl_xor(s, 8, 64);  s2 += __shfl_xor(s2, 8, 64);
    float mean = s * (1.f / 384.f);
    float var = s2 * (1.f / 384.f) - mean * mean;
    float inv = rsqrtf(var + 1e-5f);

    size_t ro = (size_t)(m0 + rloc) * 384;
    #pragma unroll
    for (int m = 0; m < 6; ++m) {
        int c0 = m * 64 + sub * 4;
        f32x4 gg = *(const f32x4*)&g[c0];
        f32x4 bb = *(const f32x4*)&be[c0];
        f32x4 ov;
        s16x4 ob2;
        #pragma unroll
        for (int j = 0; j < 4; ++j) {
            float v = (vals[m][j] - mean) * inv * gg[j] + bb[j];
            ov[j] = v;
            ob2[j] = f2bf(v);
        }
        *(f32x4*)&t[ro + c0] = ov;
        *(s16x4*)&tb[ro + c0] = ob2;
    }
}

// ---------------- fused qkv-GEMM + attention per (n,h) ---------------------
__global__ __launch_bounds__(256) void qkvattn_kernel(
    const short* __restrict__ A, const short* __restrict__ Bt,
    const float* __restrict__ bias, short* __restrict__ o)
{
    __shared__ __align__(16) char smem[76544];
    short* As0 = (short*)smem;                 // [2][128*64]
    short* Bs0 = (short*)(smem + 32768);       // [2][144*64]
    short* Qs  = (short*)smem;                 // [128][56]
    short* Ks  = (short*)(smem + 14336);       // [128][56]
    short* Vt  = (short*)(smem + 28672);       // [48][136]
    short* P   = (short*)(smem + 41728);       // [4][32][136]

    int tid = threadIdx.x;
    int w = tid >> 6, lane = tid & 63;
    int cq = lane >> 4, cl = lane & 15;
    int n = blockIdx.x >> 3, h = blockIdx.x & 7;
    int m0 = n * 128;

    // ---- phase 1: qkv GEMM ----
    int rl = lane >> 3, sl = lane & 7;
    int cb = sl ^ rl;
    const short* aptr[4];
    int arow[4];
    #pragma unroll
    for (int l = 0; l < 4; ++l) {
        arow[l] = l * 32 + w * 8;
        aptr[l] = A + (size_t)(m0 + arow[l] + rl) * 384 + cb * 8;
    }
    const short* bptr[5];
    int brow[5];
    #pragma unroll
    for (int l = 0; l < 5; ++l) {
        brow[l] = (l < 4) ? (l * 32 + w * 8) : (128 + w * 8);
        int r = brow[l] + rl;
        int g0 = (r >= 96) ? 2 : ((r >= 48) ? 1 : 0);
        int loc = r - g0 * 48;
        bptr[l] = Bt + (size_t)(g0 * 384 + h * 48 + loc) * 384 + cb * 8;
    }

    f32x4 acc[2][9];
    #pragma unroll
    for (int mt = 0; mt < 2; ++mt)
        #pragma unroll
        for (int nt = 0; nt < 9; ++nt)
            acc[mt][nt] = (f32x4){0.f, 0.f, 0.f, 0.f};

    #pragma unroll
    for (int l = 0; l < 4; ++l) { gload_lds16(aptr[l], &As0[arow[l] * 64]); aptr[l] += 64; }
    #pragma unroll
    for (int l = 0; l < 5; ++l) {
        if (l < 4 || w < 2) { gload_lds16(bptr[l], &Bs0[brow[l] * 64]); }
        bptr[l] += 64;
    }
    __syncthreads();

    for (int k = 0; k < 6; ++k) {
        int cur = k & 1;
        if (k + 1 < 6) {
            #pragma unroll
            for (int l = 0; l < 4; ++l) {
                gload_lds16(aptr[l], &As0[(cur ^ 1) * 8192 + arow[l] * 64]);
                aptr[l] += 64;
            }
            #pragma unroll
            for (int l = 0; l < 5; ++l) {
                if (l < 4 || w < 2)
                    gload_lds16(bptr[l], &Bs0[(cur ^ 1) * 9216 + brow[l] * 64]);
                bptr[l] += 64;
            }
        }
        const short* Asb = As0 + cur * 8192;
        const short* Bsb = Bs0 + cur * 9216;
        #pragma unroll
        for (int s = 0; s < 2; ++s) {
            bf16x8 afr[2], bfr[9];
            #pragma unroll
            for (int mt = 0; mt < 2; ++mt) {
                int r = w * 32 + mt * 16 + cl;
                int slot = (s * 4 + cq) ^ (r & 7);
                afr[mt] = *(const bf16x8*)&Asb[r * 64 + slot * 8];
            }
            #pragma unroll
            for (int nt = 0; nt < 9; ++nt) {
                int r = nt * 16 + cl;
                int slot = (s * 4 + cq) ^ (r & 7);
                bfr[nt] = *(const bf16x8*)&Bsb[r * 64 + slot * 8];
            }
            #pragma unroll
            for (int mt = 0; mt < 2; ++mt)
                #pragma unroll
                for (int nt = 0; nt < 9; ++nt)
                    acc[mt][nt] = __builtin_amdgcn_mfma_f32_16x16x32_bf16(
                        afr[mt], bfr[nt], acc[mt][nt], 0, 0, 0);
        }
        __syncthreads();
    }

    // ---- epilogue: +bias, bf16 -> Qs/Ks (row-major) and Vt (transposed) ----
    const float* bh = bias + h * 48;
    #pragma unroll
    for (int mt = 0; mt < 2; ++mt) {
        #pragma unroll
        for (int nt = 0; nt < 9; ++nt) {
            int grp = nt / 3;
            int col = (nt - grp * 3) * 16 + cl;     // 0..47 within group
            float bb = bh[grp * 384 + col];
            if (grp == 2) {
                int row0 = w * 32 + mt * 16 + cq * 4;
                s16x4 pv;
                #pragma unroll
                for (int rg = 0; rg < 4; ++rg) pv[rg] = f2bf(acc[mt][nt][rg] + bb);
                *(s16x4*)&Vt[col * 136 + row0] = pv;
            } else {
                short* dst = (grp == 0) ? Qs : Ks;
                #pragma unroll
                for (int rg = 0; rg < 4; ++rg) {
                    int row = w * 32 + mt * 16 + cq * 4 + rg;
                    dst[row * 56 + col] = f2bf(acc[mt][nt][rg] + bb);
                }
            }
        }
    }
    __syncthreads();   // Qs/Ks/Vt ready for all waves

    // ---- phase 2: attention (R23 structure, LDS sources) ----
    const bf16x8 zf = (bf16x8){0, 0, 0, 0, 0, 0, 0, 0};
    bf16x8 qf[2][2];
    #pragma unroll
    for (int mt = 0; mt < 2; ++mt) {
        int r = w * 32 + mt * 16 + cl;
        qf[mt][0] = *(const bf16x8*)&Qs[r * 56 + cq * 8];
        qf[mt][1] = (cq < 2) ? *(const bf16x8*)&Qs[r * 56 + 32 + cq * 8] : zf;
    }

    f32x4 sacc[2][8];
    #pragma unroll
    for (int mt = 0; mt < 2; ++mt)
        #pragma unroll
        for (int kt = 0; kt < 8; ++kt)
            sacc[mt][kt] = (f32x4){0.f, 0.f, 0.f, 0.f};

    #pragma unroll
    for (int kt = 0; kt < 8; ++kt) {
        int r = kt * 16 + cl;
        bf16x8 kf0 = *(const bf16x8*)&Ks[r * 56 + cq * 8];
        bf16x8 kf1 = (cq < 2) ? *(const bf16x8*)&Ks[r * 56 + 32 + cq * 8] : zf;
        #pragma unroll
        for (int mt = 0; mt < 2; ++mt) {
            sacc[mt][kt] = __builtin_amdgcn_mfma_f32_16x16x32_bf16(
                qf[mt][0], kf0, sacc[mt][kt], 0, 0, 0);
            sacc[mt][kt] = __builtin_amdgcn_mfma_f32_16x16x32_bf16(
                qf[mt][1], kf1, sacc[mt][kt], 0, 0, 0);
        }
    }

    const float temp = 0.14433756729740643f;  // 1/sqrt(48)
    short* Pw = P + w * 4352;
    float denom[2][4];
    #pragma unroll
    for (int mt = 0; mt < 2; ++mt) {
        #pragma unroll
        for (int rg = 0; rg < 4; ++rg) {
            float mx = sacc[mt][0][rg];
            #pragma unroll
            for (int kt = 1; kt < 8; ++kt) mx = fmaxf(mx, sacc[mt][kt][rg]);
            mx = fmaxf(mx, __shfl_xor(mx, 1, 64));
            mx = fmaxf(mx, __shfl_xor(mx, 2, 64));
            mx = fmaxf(mx, __shfl_xor(mx, 4, 64));
            mx = fmaxf(mx, __shfl_xor(mx, 8, 64));
            int row = mt * 16 + cq * 4 + rg;
            float se = 0.f;
            #pragma unroll
            for (int kt = 0; kt < 8; ++kt) {
                float p = __expf(temp * (sacc[mt][kt][rg] - mx));
                se += p;
                Pw[row * 136 + kt * 16 + cl] = f2bf(p);
            }
            se += __shfl_xor(se, 1, 64);
            se += __shfl_xor(se, 2, 64);
            se += __shfl_xor(se, 4, 64);
            se += __shfl_xor(se, 8, 64);
            denom[mt][rg] = se;
        }
    }

    f32x4 oacc[2][3];
    #pragma unroll
    for (int mt = 0; mt < 2; ++mt)
        #pragma unroll
        for (int nt = 0; nt < 3; ++nt)
            oacc[mt][nt] = (f32x4){0.f, 0.f, 0.f, 0.f};

    #pragma unroll
    for (int ks = 0; ks < 4; ++ks) {
        bf16x8 paf[2];
        #pragma unroll
        for (int mt = 0; mt < 2; ++mt)
            paf[mt] = *(const bf16x8*)&Pw[(mt * 16 + cl) * 136 + ks * 32 + cq * 8];
        #pragma unroll
        for (int nt = 0; nt < 3; ++nt) {
            bf16x8 vf = *(const bf16x8*)&Vt[(nt * 16 + cl) * 136 + ks * 32 + cq * 8];
            #pragma unroll
            for (int mt = 0; mt < 2; ++mt)
                oacc[mt][nt] = __builtin_amdgcn_mfma_f32_16x16x32_bf16(
                    paf[mt], vf, oacc[mt][nt], 0, 0, 0);
        }
    }

    #pragma unroll
    for (int mt = 0; mt < 2; ++mt) {
        #pragma unroll
        for (int rg = 0; rg < 4; ++rg) {
            float inv = 1.f / denom[mt][rg];
            int qrow = w * 32 + mt * 16 + cq * 4 + rg;
            short* op = o + ((size_t)n * 128 + qrow) * 384 + h * 48;
            #pragma unroll
            for (int nt = 0; nt < 3; ++nt)
                op[nt * 16 + cl] = f2bf(oacc[mt][nt][rg] * inv);
        }
    }
}

// ---------------- classifier head ------------------------------------------
__global__ __launch_bounds__(384) void head_kernel(
    const float* __restrict__ t, const float* __restrict__ cls_w,
    const float* __restrict__ cls_b, float* __restrict__ out)
{
    int n = blockIdx.x, d = threadIdx.x;
    float s = 0.f;
    for (int l = 0; l < 128; ++l) s += t[((size_t)n * 128 + l) * 384 + d];
    float p = s * (1.f / 128.f) * cls_w[d];
    #pragma unroll
    for (int off = 32; off > 0; off >>= 1) p += __shfl_xor(p, off, 64);
    __shared__ float red[6];
    if ((threadIdx.x & 63) == 0) red[threadIdx.x >> 6] = p;
    __syncthreads();
    if (threadIdx.x == 0) {
        float tot = red[0] + red[1] + red[2] + red[3] + red[4] + red[5];
        out[n] = tot + cls_b[0];
    }
}

// ---------------------------------------------------------------------------
extern "C" void kernel_launch(void* const* d_in, const int* in_sizes, int n_in,
                              void* d_out, int out_size, void* d_ws, size_t ws_size,
                              hipStream_t stream) {
    (void)n_in; (void)out_size; (void)ws_size;
    const float* x   = (const float*)d_in[0];
    const float* cw0 = (const float*)d_in[1];
    const float* cb0 = (const float*)d_in[2];
    const float* cw1 = (const float*)d_in[3];
    const float* cb1 = (const float*)d_in[4];
    const float* cw2 = (const float*)d_in[5];
    const float* cb2 = (const float*)d_in[6];
    const float* ew  = (const float*)d_in[7];
    const float* eb  = (const float*)d_in[8];
    bool dict_order = (in_sizes[10] == 589824);
    const float *Wq, *Wk, *Wv, *Wo, *W1, *W2, *bq, *bk, *bv, *bo, *b1, *b2;
    if (dict_order) {
        Wq = (const float*)d_in[9];  Wk = (const float*)d_in[10];
        Wv = (const float*)d_in[11]; Wo = (const float*)d_in[12];
        W1 = (const float*)d_in[13]; W2 = (const float*)d_in[14];
        bq = (const float*)d_in[15]; bk = (const float*)d_in[16];
        bv = (const float*)d_in[17]; bo = (const float*)d_in[18];
        b1 = (const float*)d_in[19]; b2 = (const float*)d_in[20];
    } else {
        Wq = (const float*)d_in[9];  bq = (const float*)d_in[10];
        Wk = (const float*)d_in[11]; bk = (const float*)d_in[12];
        Wv = (const float*)d_in[13]; bv = (const float*)d_in[14];
        Wo = (const float*)d_in[15]; bo = (const float*)d_in[16];
        W1 = (const float*)d_in[17]; b1 = (const float*)d_in[18];
        W2 = (const float*)d_in[19]; b2 = (const float*)d_in[20];
    }
    const float* g1  = (const float*)d_in[21];
    const float* be1 = (const float*)d_in[22];
    const float* g2  = (const float*)d_in[23];
    const float* be2 = (const float*)d_in[24];
    const float* clw = (const float*)d_in[25];
    const float* clb = (const float*)d_in[26];

    // ---- workspace layout (bytes) ----
    char* wp = (char*)d_ws;
    float* pe    = (float*)wp; wp += 196608;      // 128*384 f32
    short* featb = (short*)wp; wp += 33554432;    // 8192*2048 bf16 (reused as FFN hidden)
    float* t     = (float*)wp; wp += 12582912;    // 8192*384 f32
    short* tb    = (short*)wp; wp += 6291456;     // 8192*384 bf16
    short* qkvb  = (short*)wp; wp += 18874368;    // (unused after R26)
    short* ob    = (short*)wp; wp += 6291456;     // 8192*384 bf16 (attn out)
    short* ewT   = (short*)wp; wp += 1572864;     // 384 x 2048
    short* WqkvT = (short*)wp; wp += 3538944;     // 4 x 1152 x 384
    short* WoT   = (short*)wp; wp += 1179648;     // 4 x 384 x 384
    short* W1T   = (short*)wp; wp += 4718592;     // 4 x 1536 x 384
    short* W2T   = (short*)wp; wp += 4718592;     // 4 x 384 x 1536
    float* bqkv  = (float*)wp; wp += 18432;       // 4 x 1152 f32
    short* w2T   = (short*)wp; wp += 16384;       // 64 x 128 bf16 (conv2)
    short* w1m   = (short*)wp; wp += 2048;        // 2 x 16 x 32 bf16 (conv1)
    short* hb    = featb;                         // FFN hidden 8192*1536 bf16
    (void)qkvb;

    const int ROWS = 8192;

    prep_kernel<<<7926, 256, 0, stream>>>(ew, Wq, Wk, Wv, Wo, W1, W2,
                                          bq, bk, bv, cw2, cw1,
                                          ewT, WqkvT, WoT, W1T, W2T,
                                          pe, bqkv, w2T, w1m);
    cnn_kernel<<<8192, 64, 0, stream>>>(x, cw0, cb0, w1m, cb1, w2T, cb2, featb);

    // t/tb = relu(feat @ ew + eb) + pe
    gemm_bf16<29><<<dim3(6, 64), 256, 0, stream>>>(featb, ewT, eb, nullptr, pe,
                                                   t, tb, ROWS, 384, 2048);
    for (int i = 0; i < 4; ++i) {
        const short* WqkvTi = WqkvT + (size_t)i * 442368;
        const short* WoTi = WoT + (size_t)i * 147456;
        const short* W1Ti = W1T + (size_t)i * 589824;
        const short* W2Ti = W2T + (size_t)i * 589824;
        // ob = attn(qkv(tb)) fused
        qkvattn_kernel<<<512, 256, 0, stream>>>(tb, WqkvTi, bqkv + i * 1152, ob);
        // t/tb = LN(o @ Wo + bo + t)
        gemm_ln<<<256, 512, 0, stream>>>(ob, WoTi, bo + i * 384, t,
            g1 + i * 384, be1 + i * 384, t, tb, 384);
        // hidden = relu(t @ W1 + b1)
        gemm_bf16_wide<17><<<dim3(12, 64), 256, 0, stream>>>(tb, W1Ti,
            b1 + i * 1536, nullptr, hb, ROWS, 1536, 384);
        // t/tb = LN(hidden @ W2 + b2 + t)
        gemm_ln<<<256, 512, 0, stream>>>(hb, W2Ti, b2 + i * 384, t,
            g2 + i * 384, be2 + i * 384, t, tb, 1536);
    }
    head_kernel<<<64, 384, 0, stream>>>(t, clw, clb, (float*)d_out);
}